// Round 3
// baseline (212.437 us; speedup 1.0000x reference)
//
#include <hip/hip_runtime.h>
#include <hip/hip_bf16.h>
#include <stdint.h>

// Round-12 change: abandon the reg-staged fp32-convert QKV GEMM (3 rounds
// stuck at ~500 TF; reg-staging structurally below the DMA path). prep now
// converts fp32 qkv -> f16 (streaming, same cvt_pkrtz bits), and gemm_bt is
// the pure global_load_lds m97 2-barrier structure for BOTH dtype modes:
// LDS 34.8 KB -> 4 blocks/CU, no staging VALU in the K-loop.
// Plus T1 XCD-aware tile swizzle on gemm_bt (per-z, W panel per XCD),
// gemm_o, and attn (8 t-blocks sharing a K/V slice -> one XCD L2).

typedef unsigned short ushort_t;
typedef __attribute__((ext_vector_type(8))) _Float16 half8;  // MFMA A/B frag
typedef __attribute__((ext_vector_type(4))) float floatx4;   // MFMA C/D frag
typedef __attribute__((ext_vector_type(4))) unsigned int uint4v;
typedef __attribute__((ext_vector_type(4))) float float4v;
typedef __attribute__((ext_vector_type(2))) float float2v;
typedef __attribute__((ext_vector_type(8))) short short8;

#define B_ 4
#define T_ 1024
#define S_ 1024
#define E_ 1024
#define H_ 16
#define DH_ 64

#define MASK_NEG  (-1e30f)
#define MEXP_OFF  (-11.5415603189f)   // -8 * log2(e): f16-safe fixed softmax offset
#define L2E_      (1.44269504089f)

__device__ __forceinline__ float bf2f(ushort_t h) {
  return __builtin_bit_cast(float, ((unsigned int)h) << 16);
}
__device__ __forceinline__ ushort_t f2bf(float f) {
  unsigned int u = __builtin_bit_cast(unsigned int, f);
  u += 0x7fffu + ((u >> 16) & 1u);  // RNE
  return (ushort_t)(u >> 16);
}
__device__ __forceinline__ unsigned int pack2h(float a, float b) {
  return __builtin_bit_cast(unsigned int, __builtin_amdgcn_cvt_pkrtz(a, b));
}

__device__ __forceinline__ void gload_lds16(const ushort_t* g, ushort_t* l) {
  __builtin_amdgcn_global_load_lds(
      (const __attribute__((address_space(1))) unsigned int*)g,
      (__attribute__((address_space(3))) unsigned int*)l, 16, 0, 0);
}

// ---- prep: self-detect dtypes; biases+masks; W -> f16; qkv -> f16 (from
// fp32 OR bf16 — gemm_bt always consumes pre-converted f16 via DMA).
#define QKV_V4 (3LL << 19)
#define W_V4   (4LL << 17)
__global__ void prep_convert(
    const void* __restrict__ q, const void* __restrict__ k, const void* __restrict__ v,
    const void* __restrict__ w0, const void* __restrict__ w1,
    const void* __restrict__ w2, const void* __restrict__ w3,
    const void* __restrict__ b0, const void* __restrict__ b1,
    const void* __restrict__ b2, const void* __restrict__ b3,
    const int* __restrict__ kpm, const int* __restrict__ lm,
    int* __restrict__ flags, float* __restrict__ B4,
    float* __restrict__ mvG, float* __restrict__ mvL,
    uint4v* __restrict__ dqkv, uint4v* __restrict__ dw)
{
  __shared__ int sf[2];
  const int tid = threadIdx.x;
  if (tid < 64) {
    const unsigned w = ((const unsigned int*)q)[tid];
    const unsigned e = (w >> 7) & 0xFFu;
    const unsigned long long bal = __ballot(e >= 100u && e <= 135u);
    const unsigned long long big = __ballot(((const unsigned int*)kpm)[tid] > 1u);
    if (tid == 0) {
      sf[0] = (__popcll(bal) < 40) ? 1 : 0;
      sf[1] = big ? 1 : 0;
      if (blockIdx.x == 0) { flags[0] = sf[0]; flags[1] = sf[1]; }
    }
  }
  __syncthreads();
  const int fp32 = sf[0], int8f = sf[1];

  const long long i0 = (long long)blockIdx.x * 256 + tid;
  if (i0 < 4096) {
    const int seg = (int)(i0 >> 10), j = (int)(i0 & 1023);
    const void* s = seg == 0 ? b0 : (seg == 1 ? b1 : (seg == 2 ? b2 : b3));
    B4[i0] = fp32 ? ((const float*)s)[j] : bf2f(((const ushort_t*)s)[j]);
  } else if (i0 < 12288) {
    const int kk = (int)(i0 - 4096);
    const int* src = (kk < B_ * S_) ? kpm : lm;
    float* dst = (kk < B_ * S_) ? mvG : mvL;
    const int j = kk & (B_ * S_ - 1);
    const int mv = int8f ? (int)((const unsigned char*)src)[j] : src[j];
    dst[j] = mv ? MASK_NEG : MEXP_OFF;
  }

  const long long total = QKV_V4 + W_V4;   // qkv always converted now
  const long long stride = (long long)gridDim.x * blockDim.x;
  for (long long i = i0; i < total; i += stride) {
    const void* s;
    long long j;
    uint4v* dst;
    long long di;
    if (i < QKV_V4) {
      const int seg = (int)(i >> 19);
      j = i & ((1LL << 19) - 1);
      s = seg == 0 ? q : (seg == 1 ? k : v);
      dst = dqkv; di = i;
    } else {
      const long long t = i - QKV_V4;
      const int seg = (int)(t >> 17);
      j = t & ((1LL << 17) - 1);
      s = seg == 0 ? w0 : (seg == 1 ? w1 : (seg == 2 ? w2 : w3));
      dst = dw; di = t;
    }
    uint4v outw;
    if (fp32) {
      const float4v* f = (const float4v*)s;
      const float4v a = f[2 * j], b = f[2 * j + 1];
      outw[0] = pack2h(a[0], a[1]); outw[1] = pack2h(a[2], a[3]);
      outw[2] = pack2h(b[0], b[1]); outw[3] = pack2h(b[2], b[3]);
    } else {
      const uint4v in = ((const uint4v*)s)[j];
#pragma unroll
      for (int t4 = 0; t4 < 4; t4++)
        outw[t4] = pack2h(bf2f((ushort_t)(in[t4] & 0xFFFFu)),
                          bf2f((ushort_t)(in[t4] >> 16)));
    }
    dst[di] = outw;
  }
}

// ---- QKV GEMM: C[M][N] = A[M][K] @ W[N][K]^T, pure-DMA m97 structure.
// 128x128 tile, BK=64, LDS 34.8 KB (4 blocks/CU). XCD swizzle: each XCD
// owns one n-panel per z-plane (W panel fetched once per XCD L2).
__global__ __launch_bounds__(256, 4) void gemm_bt(
    const ushort_t* __restrict__ Ah0, const ushort_t* __restrict__ Ah1, const ushort_t* __restrict__ Ah2,
    const ushort_t* __restrict__ W0, const ushort_t* __restrict__ W1, const ushort_t* __restrict__ W2,
    const float* __restrict__ b0p, const float* __restrict__ b1p, const float* __restrict__ b2p,
    void* __restrict__ C0, void* __restrict__ C1, ushort_t* __restrict__ vt,
    int N, int K, float scale0)
{
  __shared__ ushort_t smem[17408];   // 34816 B: As 16K | Ws 16K | epilogue 128x136
  ushort_t* As = smem;
  ushort_t* Ws = smem + 8192;

  const int z = blockIdx.z;
  const ushort_t* Ah   = z == 0 ? Ah0 : (z == 1 ? Ah1 : Ah2);
  const ushort_t* W    = z == 0 ? W0 : (z == 1 ? W1 : W2);
  const float* bias    = z == 0 ? b0p : (z == 1 ? b1p : b2p);
  const float scale    = (z == 0) ? scale0 : 1.0f;

  // XCD-aware tile swizzle within this z-plane (256 blocks, 256%8==0).
  const int op  = blockIdx.y * 32 + blockIdx.x;
  const int swz = (op & 7) * 32 + (op >> 3);
  const int m0  = (swz & 31) * 128;
  const int n0  = (swz >> 5) * 128;

  const int tid  = threadIdx.x;
  const int wave = tid >> 6;
  const int lane = tid & 63;
  const int quad = lane >> 4;
  const int l16  = lane & 15;
  const int rx   = l16 & 7;
  const int wm   = (wave >> 1) * 64;
  const int wn   = (wave & 1) * 64;

  const ushort_t* Ab = Ah + (size_t)m0 * K;
  const ushort_t* Wb = W + (size_t)n0 * K;

  floatx4 acc[4][4];
#pragma unroll
  for (int i = 0; i < 4; i++)
#pragma unroll
    for (int j = 0; j < 4; j++) acc[i][j] = (floatx4){0.f, 0.f, 0.f, 0.f};

  const int srow = tid >> 3;
  const int cc   = tid & 7;
  const int ldsw = wave * 512;

  for (int k0 = 0; k0 < K; k0 += 64) {
    __syncthreads();
#pragma unroll
    for (int it = 0; it < 4; ++it) {
      const int row = it * 32 + srow;
      const int sw = (cc ^ (row & 7)) * 8;
      gload_lds16(Ab + (size_t)row * K + k0 + sw, &As[it * 2048 + ldsw]);
      gload_lds16(Wb + (size_t)row * K + k0 + sw, &Ws[it * 2048 + ldsw]);
    }
    __syncthreads();
#pragma unroll
    for (int kk = 0; kk < 2; ++kk) {
      half8 af[4], wf[4];
#pragma unroll
      for (int i = 0; i < 4; i++)
        af[i] = *(const half8*)&As[(wm + i * 16 + l16) * 64 + (((kk * 4 + quad) ^ rx) * 8)];
#pragma unroll
      for (int i = 0; i < 4; i++)
        wf[i] = *(const half8*)&Ws[(wn + i * 16 + l16) * 64 + (((kk * 4 + quad) ^ rx) * 8)];
#pragma unroll
      for (int i = 0; i < 4; i++)
#pragma unroll
        for (int j = 0; j < 4; j++)
          acc[i][j] = __builtin_amdgcn_mfma_f32_16x16x32_f16(af[i], wf[j], acc[i][j], 0, 0, 0);
    }
  }

  __syncthreads();  // staging done; smem reused by epilogue

  if (z == 2) {
    // Ct[n][m] in LDS, pkrtz 8B packed -> coalesced Vt rows (f16)
#pragma unroll
    for (int j = 0; j < 4; j++) {
      const int n_loc = wn + j * 16 + l16;
      const float bv = bias[n0 + n_loc];
#pragma unroll
      for (int i = 0; i < 4; i++) {
        const int m_base = wm + i * 16 + quad * 4;
        unsigned int* p = (unsigned int*)&smem[n_loc * 136 + m_base];
        p[0] = pack2h(acc[i][j][0] + bv, acc[i][j][1] + bv);
        p[1] = pack2h(acc[i][j][2] + bv, acc[i][j][3] + bv);
      }
    }
    __syncthreads();
    const int b = m0 >> 10;
    const int sb0 = m0 & 1023;
#pragma unroll
    for (int c = 0; c < 8; c++) {
      const int id = c * 256 + tid;
      const int n_loc = id >> 4, cm = (id & 15) * 8;
      const short8 v = *(const short8*)&smem[n_loc * 136 + cm];
      *(short8*)&vt[((size_t)(b * 1024 + n0 + n_loc) << 10) + sb0 + cm] = v;
    }
    return;
  }

  void* C = z == 0 ? C0 : C1;
#pragma unroll
  for (int j = 0; j < 4; j++) {
    const int n_loc = wn + j * 16 + l16;
    const float bv = bias[n0 + n_loc];
#pragma unroll
    for (int i = 0; i < 4; i++) {
      const int m_base = wm + i * 16 + quad * 4;
#pragma unroll
      for (int r = 0; r < 4; r++)
        ((_Float16*)smem)[(m_base + r) * 136 + n_loc] =
            (_Float16)((acc[i][j][r] + bv) * scale);
    }
  }
  __syncthreads();
#pragma unroll
  for (int c = 0; c < 8; c++) {
    const int id = c * 256 + tid;
    const int m_loc = id >> 4, cn = (id & 15) * 8;
    const short8 v = *(const short8*)&smem[m_loc * 136 + cn];
    *(short8*)&((ushort_t*)C)[(size_t)(m0 + m_loc) * N + n0 + cn] = v;
  }
}

// ---- O-projection GEMM: 128m x 64n tile, 2-phase double-buffered staging.
// LDS: As0 16K | As1 16K | Ws0 8K | Ws1 8K = 48 KB. XCD swizzle (cpx=64).
__global__ __launch_bounds__(256) void gemm_o(
    const ushort_t* __restrict__ A, const ushort_t* __restrict__ W,
    const float* __restrict__ bias, void* __restrict__ C,
    int N, int K, const int* __restrict__ flags)
{
  __shared__ ushort_t smem[24576];

  const int tid  = threadIdx.x;
  const int wave = tid >> 6;
  const int lane = tid & 63;
  const int quad = lane >> 4;
  const int l16  = lane & 15;
  const int rx   = l16 & 7;
  const int wm   = (wave >> 1) * 64;
  const int wn   = (wave & 1) * 32;

  // XCD swizzle: 512 blocks, each XCD owns 2 n-panels (W reuse in L2).
  const int op  = blockIdx.y * 32 + blockIdx.x;
  const int swz = (op & 7) * 64 + (op >> 3);
  const int m0  = (swz & 31) * 128;
  const int n0  = (swz >> 5) * 64;
  const bool wf32 = flags[0] != 0;

  const ushort_t* Ab = A + (size_t)m0 * K;
  const ushort_t* Wb = W + (size_t)n0 * K;

  floatx4 acc[4][2];
#pragma unroll
  for (int i = 0; i < 4; i++)
#pragma unroll
    for (int j = 0; j < 2; j++) acc[i][j] = (floatx4){0.f, 0.f, 0.f, 0.f};

  const int srow = tid >> 3;
  const int cc   = tid & 7;
  const int ldsw = wave * 512;

  auto stage_o = [&](int k0, int bsel) {
    ushort_t* Asb = smem + bsel * 8192;
    ushort_t* Wsb = smem + 16384 + bsel * 4096;
#pragma unroll
    for (int it = 0; it < 4; ++it) {
      const int row = it * 32 + srow;
      const int sw  = (cc ^ (row & 7)) * 8;
      gload_lds16(Ab + (size_t)row * K + k0 + sw, &Asb[it * 2048 + ldsw]);
      if (it < 2)
        gload_lds16(Wb + (size_t)row * K + k0 + sw, &Wsb[it * 2048 + ldsw]);
    }
  };

  stage_o(0, 0);
  __syncthreads();
  for (int k0 = 0, s = 0; k0 < K; k0 += 64, ++s) {
    const int cur = s & 1;
    if (k0 + 64 < K) stage_o(k0 + 64, cur ^ 1);   // issue-early into other buf
    const ushort_t* Asb = smem + cur * 8192;
    const ushort_t* Wsb = smem + 16384 + cur * 4096;
#pragma unroll
    for (int kk = 0; kk < 2; ++kk) {
      half8 af[4], wf[2];
#pragma unroll
      for (int i = 0; i < 4; i++)
        af[i] = *(const half8*)&Asb[(wm + i * 16 + l16) * 64 + (((kk * 4 + quad) ^ rx) * 8)];
#pragma unroll
      for (int j = 0; j < 2; j++)
        wf[j] = *(const half8*)&Wsb[(wn + j * 16 + l16) * 64 + (((kk * 4 + quad) ^ rx) * 8)];
#pragma unroll
      for (int i = 0; i < 4; i++)
#pragma unroll
        for (int j = 0; j < 2; j++)
          acc[i][j] = __builtin_amdgcn_mfma_f32_16x16x32_f16(af[i], wf[j], acc[i][j], 0, 0, 0);
    }
    __syncthreads();   // drain-late: prefetch latency was covered by MFMA
  }

  if (wf32) {
#pragma unroll
    for (int j = 0; j < 2; j++) {
      const int n = n0 + wn + j * 16 + l16;
      const float bv = bias[n];
#pragma unroll
      for (int i = 0; i < 4; i++) {
        const int mrow = m0 + wm + i * 16 + quad * 4;
#pragma unroll
        for (int r = 0; r < 4; r++)
          ((float*)C)[(size_t)(mrow + r) * N + n] = acc[i][j][r] + bv;
      }
    }
  } else {
#pragma unroll
    for (int j = 0; j < 2; j++) {
      const int n_loc = wn + j * 16 + l16;
      const float bv = bias[n0 + n_loc];
#pragma unroll
      for (int i = 0; i < 4; i++) {
        const int m_base = wm + i * 16 + quad * 4;
#pragma unroll
        for (int r = 0; r < 4; r++)
          smem[(m_base + r) * 72 + n_loc] = f2bf(acc[i][j][r] + bv);
      }
    }
    __syncthreads();
#pragma unroll
    for (int c = 0; c < 4; c++) {
      const int id = c * 256 + tid;
      const int m_loc = id >> 3, cn = (id & 7) * 8;
      const short8 v = *(const short8*)&smem[m_loc * 72 + cn];
      *(short8*)&((ushort_t*)C)[(size_t)(m0 + m_loc) * N + n0 + cn] = v;
    }
  }
}

// ---- Flash attention (f16): 512-thread blocks, t-tile 128 (8 waves x 16).
// K/V double-buffered, one barrier per tile. XCD swizzle: the 8 t-blocks
// sharing one (b,h) K/V slice land on one XCD (~2 MB/XCD, L2-resident).
__global__ __launch_bounds__(512) void attn(
    const ushort_t* __restrict__ Q, const ushort_t* __restrict__ K,
    const ushort_t* __restrict__ Vt,
    const float* __restrict__ mvG, const float* __restrict__ mvL,
    ushort_t* __restrict__ O)
{
  __shared__ ushort_t Qs[128 * 64];
  __shared__ ushort_t Ks[2][64 * 64];
  __shared__ ushort_t Vs[2][64 * 64];
  __shared__ float mvb[S_];
  __shared__ _Float16 Ps[8][16 * 72];

  // XCD swizzle: 512 blocks, cpx=64; decode (t,h,b) from swizzled id.
  const int orig = (blockIdx.z * 16 + blockIdx.y) * 8 + blockIdx.x;
  const int swz  = (orig & 7) * 64 + (orig >> 3);
  const int t0 = (swz & 7) * 128;
  const int h  = (swz >> 3) & 15;
  const int b  = swz >> 7;

  const int tid = threadIdx.x, wave = tid >> 6, lane = tid & 63;
  const int quad = lane >> 4, l16 = lane & 15;
  const int rx = l16 & 7;

  const float* msel = (h < (H_ / 2)) ? mvG : mvL;
  ((float2v*)mvb)[tid] = ((const float2v*)(msel + b * S_))[tid];

  const int srow = tid >> 3, cc = tid & 7;
  const int sc8 = (cc ^ (srow & 7)) * 8;

  const ushort_t* Kb = K + (size_t)b * S_ * E_ + h * DH_;
  const ushort_t* Vb = Vt + (size_t)((b * H_ + h) * DH_) * S_;

  auto stageKV = [&](int st, int bsel) {
    const int s0 = st * 64;
    gload_lds16(Kb + (size_t)(s0 + srow) * E_ + sc8, &Ks[bsel][wave * 512]);
    gload_lds16(Vb + (size_t)srow * S_ + s0 + sc8, &Vs[bsel][wave * 512]);
  };

  const ushort_t* Qb = Q + (size_t)(b * T_ + t0) * E_ + h * DH_;
#pragma unroll
  for (int it = 0; it < 2; ++it) {
    const int row = it * 64 + srow;
    gload_lds16(Qb + (size_t)row * E_ + ((cc ^ (row & 7)) * 8),
                &Qs[it * 4096 + wave * 512]);
  }
  stageKV(0, 0);
  __syncthreads();

  const half8 qf0 = *(const half8*)&Qs[(wave * 16 + l16) * 64 + ((quad ^ rx) * 8)];
  const half8 qf1 = *(const half8*)&Qs[(wave * 16 + l16) * 64 + (((quad + 4) ^ rx) * 8)];

  float lsum[4];
  floatx4 oa[4];
#pragma unroll
  for (int r = 0; r < 4; r++) lsum[r] = 0.0f;
#pragma unroll
  for (int i = 0; i < 4; i++) oa[i] = (floatx4){0.f, 0.f, 0.f, 0.f};

  for (int st = 0; st < 16; ++st) {
    const int cur = st & 1;
    if (st + 1 < 16) stageKV(st + 1, cur ^ 1);   // issue-early into other buf
    const int s0 = st * 64;

    floatx4 sc[4];
#pragma unroll
    for (int j = 0; j < 4; j++) {
      const half8 kf0 = *(const half8*)&Ks[cur][(j * 16 + l16) * 64 + ((quad ^ rx) * 8)];
      const half8 kf1 = *(const half8*)&Ks[cur][(j * 16 + l16) * 64 + (((quad + 4) ^ rx) * 8)];
      floatx4 zz = (floatx4){0.f, 0.f, 0.f, 0.f};
      zz = __builtin_amdgcn_mfma_f32_16x16x32_f16(qf0, kf0, zz, 0, 0, 0);
      zz = __builtin_amdgcn_mfma_f32_16x16x32_f16(qf1, kf1, zz, 0, 0, 0);
      sc[j] = zz;
    }

#pragma unroll
    for (int j = 0; j < 4; j++) {
      const float mv = mvb[s0 + j * 16 + l16];
#pragma unroll
      for (int r = 0; r < 4; r++) {
        const float p = exp2f(fmaf(sc[j][r], L2E_, mv));
        lsum[r] += p;
        Ps[wave][(quad * 4 + r) * 72 + j * 16 + l16] = (_Float16)p;
      }
    }

    const half8 pa0 = *(const half8*)&Ps[wave][l16 * 72 + quad * 8];
    const half8 pa1 = *(const half8*)&Ps[wave][l16 * 72 + 32 + quad * 8];
#pragma unroll
    for (int i = 0; i < 4; i++) {
      const half8 vb0 = *(const half8*)&Vs[cur][(i * 16 + l16) * 64 + ((quad ^ rx) * 8)];
      const half8 vb1 = *(const half8*)&Vs[cur][(i * 16 + l16) * 64 + (((quad + 4) ^ rx) * 8)];
      oa[i] = __builtin_amdgcn_mfma_f32_16x16x32_f16(pa0, vb0, oa[i], 0, 0, 0);
      oa[i] = __builtin_amdgcn_mfma_f32_16x16x32_f16(pa1, vb1, oa[i], 0, 0, 0);
    }

    __syncthreads();   // drain prefetch (covered by compute) + buf handoff
  }

#pragma unroll
  for (int r = 0; r < 4; r++) {
#pragma unroll
    for (int off = 1; off < 16; off <<= 1) lsum[r] += __shfl_xor(lsum[r], off, 64);
    const float inv = (lsum[r] > 0.0f) ? (1.0f / lsum[r]) : 0.0f;
    const int trow = t0 + wave * 16 + quad * 4 + r;
#pragma unroll
    for (int i = 0; i < 4; i++)
      ((_Float16*)O)[(size_t)(b * T_ + trow) * E_ + h * DH_ + i * 16 + l16] =
          (_Float16)(oa[i][r] * inv);
  }
}

extern "C" void kernel_launch(void* const* d_in, const int* in_sizes, int n_in,
                              void* d_out, int out_size, void* d_ws, size_t ws_size,
                              hipStream_t stream)
{
  const void* query = d_in[0];
  const void* key   = d_in[1];
  const void* value = d_in[2];
  const int* kpm    = (const int*)d_in[3];
  const int* lm     = (const int*)d_in[4];
  const void* Wq    = d_in[5];
  const void* bq    = d_in[6];
  const void* Wk    = d_in[7];
  const void* bk    = d_in[8];
  const void* Wv    = d_in[9];
  const void* bv    = d_in[10];
  const void* Wo    = d_in[11];
  const void* bo    = d_in[12];

  const size_t NE = (size_t)B_ * T_ * E_;   // 4M elements
  const size_t WE = (size_t)E_ * E_;        // 1M elements

  char* ws = (char*)d_ws;
  int*      flags  = (int*)ws;                               // 1 KB
  float*    mvG    = (float*)(ws + 1024);                    // 16 KB
  float*    mvL    = mvG + B_ * S_;                          // 16 KB
  float*    B4     = (float*)(ws + 64 * 1024);               // 16 KB
  ushort_t* W4     = (ushort_t*)(ws + 96 * 1024);            // 8 MB (f16)
  ushort_t* q_in   = (ushort_t*)(ws + 96 * 1024 + (8u << 20));  // f16 qkv
  ushort_t* k_in   = q_in + NE;
  ushort_t* v_in   = k_in + NE;
  ushort_t* q_buf  = v_in + NE;
  ushort_t* k_buf  = q_buf + NE;
  ushort_t* vt_buf = k_buf + NE;
  ushort_t* o_buf  = q_in;   // q_in dead after QKV gemm

  const float SCALING = 0.125f;  // DH^-0.5

  prep_convert<<<1024, 256, 0, stream>>>(
      query, key, value, Wq, Wk, Wv, Wo, bq, bk, bv, bo, kpm, lm,
      flags, B4, mvG, mvL, (uint4v*)q_in, (uint4v*)W4);
  gemm_bt<<<dim3(32, 8, 3), 256, 0, stream>>>(
      q_in, k_in, v_in,
      W4, W4 + WE, W4 + 2 * WE, B4, B4 + 1024, B4 + 2048,
      q_buf, k_buf, vt_buf, E_, E_, SCALING);
  attn<<<dim3(8, 16, 4), 512, 0, stream>>>(q_buf, k_buf, vt_buf, mvG, mvL, o_buf);
  gemm_o<<<dim3(32, 16), 256, 0, stream>>>(
      o_buf, W4 + 3 * WE, B4 + 3072, d_out, E_, E_, flags);
}

// Round 4
// 197.819 us; speedup vs baseline: 1.0739x; 1.0739x over previous
//
#include <hip/hip_runtime.h>
#include <hip/hip_bf16.h>
#include <stdint.h>

// Round-13 change: REVERT the gemm_bt/gemm_o XCD tile swizzles (R3's were
// backwards for M>>N: they gave each XCD one n-panel and ALL m-tiles ->
// full-A refetch per XCD; natural m-fastest round-robin already yields a
// 3MB/XCD working set). Keep: pure-DMA gemm_bt (f16 A from prep, 34.8KB LDS,
// 4 blk/CU bound), prep-side fp32->f16 qkv conversion, attn XCD swizzle
// (each XCD owns 8 (b,h) K/V slices = 2MB L2-resident) + K/V double-buffer.

typedef unsigned short ushort_t;
typedef __attribute__((ext_vector_type(8))) _Float16 half8;  // MFMA A/B frag
typedef __attribute__((ext_vector_type(4))) float floatx4;   // MFMA C/D frag
typedef __attribute__((ext_vector_type(4))) unsigned int uint4v;
typedef __attribute__((ext_vector_type(4))) float float4v;
typedef __attribute__((ext_vector_type(2))) float float2v;
typedef __attribute__((ext_vector_type(8))) short short8;

#define B_ 4
#define T_ 1024
#define S_ 1024
#define E_ 1024
#define H_ 16
#define DH_ 64

#define MASK_NEG  (-1e30f)
#define MEXP_OFF  (-11.5415603189f)   // -8 * log2(e): f16-safe fixed softmax offset
#define L2E_      (1.44269504089f)

__device__ __forceinline__ float bf2f(ushort_t h) {
  return __builtin_bit_cast(float, ((unsigned int)h) << 16);
}
__device__ __forceinline__ ushort_t f2bf(float f) {
  unsigned int u = __builtin_bit_cast(unsigned int, f);
  u += 0x7fffu + ((u >> 16) & 1u);  // RNE
  return (ushort_t)(u >> 16);
}
__device__ __forceinline__ unsigned int pack2h(float a, float b) {
  return __builtin_bit_cast(unsigned int, __builtin_amdgcn_cvt_pkrtz(a, b));
}

__device__ __forceinline__ void gload_lds16(const ushort_t* g, ushort_t* l) {
  __builtin_amdgcn_global_load_lds(
      (const __attribute__((address_space(1))) unsigned int*)g,
      (__attribute__((address_space(3))) unsigned int*)l, 16, 0, 0);
}

// ---- prep: self-detect dtypes; biases+masks; W -> f16; qkv -> f16 (from
// fp32 OR bf16 — gemm_bt always consumes pre-converted f16 via DMA).
#define QKV_V4 (3LL << 19)
#define W_V4   (4LL << 17)
__global__ void prep_convert(
    const void* __restrict__ q, const void* __restrict__ k, const void* __restrict__ v,
    const void* __restrict__ w0, const void* __restrict__ w1,
    const void* __restrict__ w2, const void* __restrict__ w3,
    const void* __restrict__ b0, const void* __restrict__ b1,
    const void* __restrict__ b2, const void* __restrict__ b3,
    const int* __restrict__ kpm, const int* __restrict__ lm,
    int* __restrict__ flags, float* __restrict__ B4,
    float* __restrict__ mvG, float* __restrict__ mvL,
    uint4v* __restrict__ dqkv, uint4v* __restrict__ dw)
{
  __shared__ int sf[2];
  const int tid = threadIdx.x;
  if (tid < 64) {
    const unsigned w = ((const unsigned int*)q)[tid];
    const unsigned e = (w >> 7) & 0xFFu;
    const unsigned long long bal = __ballot(e >= 100u && e <= 135u);
    const unsigned long long big = __ballot(((const unsigned int*)kpm)[tid] > 1u);
    if (tid == 0) {
      sf[0] = (__popcll(bal) < 40) ? 1 : 0;
      sf[1] = big ? 1 : 0;
      if (blockIdx.x == 0) { flags[0] = sf[0]; flags[1] = sf[1]; }
    }
  }
  __syncthreads();
  const int fp32 = sf[0], int8f = sf[1];

  const long long i0 = (long long)blockIdx.x * 256 + tid;
  if (i0 < 4096) {
    const int seg = (int)(i0 >> 10), j = (int)(i0 & 1023);
    const void* s = seg == 0 ? b0 : (seg == 1 ? b1 : (seg == 2 ? b2 : b3));
    B4[i0] = fp32 ? ((const float*)s)[j] : bf2f(((const ushort_t*)s)[j]);
  } else if (i0 < 12288) {
    const int kk = (int)(i0 - 4096);
    const int* src = (kk < B_ * S_) ? kpm : lm;
    float* dst = (kk < B_ * S_) ? mvG : mvL;
    const int j = kk & (B_ * S_ - 1);
    const int mv = int8f ? (int)((const unsigned char*)src)[j] : src[j];
    dst[j] = mv ? MASK_NEG : MEXP_OFF;
  }

  const long long total = QKV_V4 + W_V4;   // qkv always converted now
  const long long stride = (long long)gridDim.x * blockDim.x;
  for (long long i = i0; i < total; i += stride) {
    const void* s;
    long long j;
    uint4v* dst;
    long long di;
    if (i < QKV_V4) {
      const int seg = (int)(i >> 19);
      j = i & ((1LL << 19) - 1);
      s = seg == 0 ? q : (seg == 1 ? k : v);
      dst = dqkv; di = i;
    } else {
      const long long t = i - QKV_V4;
      const int seg = (int)(t >> 17);
      j = t & ((1LL << 17) - 1);
      s = seg == 0 ? w0 : (seg == 1 ? w1 : (seg == 2 ? w2 : w3));
      dst = dw; di = t;
    }
    uint4v outw;
    if (fp32) {
      const float4v* f = (const float4v*)s;
      const float4v a = f[2 * j], b = f[2 * j + 1];
      outw[0] = pack2h(a[0], a[1]); outw[1] = pack2h(a[2], a[3]);
      outw[2] = pack2h(b[0], b[1]); outw[3] = pack2h(b[2], b[3]);
    } else {
      const uint4v in = ((const uint4v*)s)[j];
#pragma unroll
      for (int t4 = 0; t4 < 4; t4++)
        outw[t4] = pack2h(bf2f((ushort_t)(in[t4] & 0xFFFFu)),
                          bf2f((ushort_t)(in[t4] >> 16)));
    }
    dst[di] = outw;
  }
}

// ---- QKV GEMM: C[M][N] = A[M][K] @ W[N][K]^T, pure-DMA m97 structure.
// 128x128 tile, BK=64, LDS 34.8 KB (4 blocks/CU). Natural dispatch order
// (m fastest): each XCD gets 4 m-tiles (1MB A) + W (2MB) = L2-resident.
__global__ __launch_bounds__(256, 4) void gemm_bt(
    const ushort_t* __restrict__ Ah0, const ushort_t* __restrict__ Ah1, const ushort_t* __restrict__ Ah2,
    const ushort_t* __restrict__ W0, const ushort_t* __restrict__ W1, const ushort_t* __restrict__ W2,
    const float* __restrict__ b0p, const float* __restrict__ b1p, const float* __restrict__ b2p,
    void* __restrict__ C0, void* __restrict__ C1, ushort_t* __restrict__ vt,
    int N, int K, float scale0)
{
  __shared__ ushort_t smem[17408];   // 34816 B: As 16K | Ws 16K | epilogue 128x136
  ushort_t* As = smem;
  ushort_t* Ws = smem + 8192;

  const int z = blockIdx.z;
  const ushort_t* Ah   = z == 0 ? Ah0 : (z == 1 ? Ah1 : Ah2);
  const ushort_t* W    = z == 0 ? W0 : (z == 1 ? W1 : W2);
  const float* bias    = z == 0 ? b0p : (z == 1 ? b1p : b2p);
  const float scale    = (z == 0) ? scale0 : 1.0f;

  const int m0  = blockIdx.x * 128;
  const int n0  = blockIdx.y * 128;

  const int tid  = threadIdx.x;
  const int wave = tid >> 6;
  const int lane = tid & 63;
  const int quad = lane >> 4;
  const int l16  = lane & 15;
  const int rx   = l16 & 7;
  const int wm   = (wave >> 1) * 64;
  const int wn   = (wave & 1) * 64;

  const ushort_t* Ab = Ah + (size_t)m0 * K;
  const ushort_t* Wb = W + (size_t)n0 * K;

  floatx4 acc[4][4];
#pragma unroll
  for (int i = 0; i < 4; i++)
#pragma unroll
    for (int j = 0; j < 4; j++) acc[i][j] = (floatx4){0.f, 0.f, 0.f, 0.f};

  const int srow = tid >> 3;
  const int cc   = tid & 7;
  const int ldsw = wave * 512;

  for (int k0 = 0; k0 < K; k0 += 64) {
    __syncthreads();
#pragma unroll
    for (int it = 0; it < 4; ++it) {
      const int row = it * 32 + srow;
      const int sw = (cc ^ (row & 7)) * 8;
      gload_lds16(Ab + (size_t)row * K + k0 + sw, &As[it * 2048 + ldsw]);
      gload_lds16(Wb + (size_t)row * K + k0 + sw, &Ws[it * 2048 + ldsw]);
    }
    __syncthreads();
#pragma unroll
    for (int kk = 0; kk < 2; ++kk) {
      half8 af[4], wf[4];
#pragma unroll
      for (int i = 0; i < 4; i++)
        af[i] = *(const half8*)&As[(wm + i * 16 + l16) * 64 + (((kk * 4 + quad) ^ rx) * 8)];
#pragma unroll
      for (int i = 0; i < 4; i++)
        wf[i] = *(const half8*)&Ws[(wn + i * 16 + l16) * 64 + (((kk * 4 + quad) ^ rx) * 8)];
#pragma unroll
      for (int i = 0; i < 4; i++)
#pragma unroll
        for (int j = 0; j < 4; j++)
          acc[i][j] = __builtin_amdgcn_mfma_f32_16x16x32_f16(af[i], wf[j], acc[i][j], 0, 0, 0);
    }
  }

  __syncthreads();  // staging done; smem reused by epilogue

  if (z == 2) {
    // Ct[n][m] in LDS, pkrtz 8B packed -> coalesced Vt rows (f16)
#pragma unroll
    for (int j = 0; j < 4; j++) {
      const int n_loc = wn + j * 16 + l16;
      const float bv = bias[n0 + n_loc];
#pragma unroll
      for (int i = 0; i < 4; i++) {
        const int m_base = wm + i * 16 + quad * 4;
        unsigned int* p = (unsigned int*)&smem[n_loc * 136 + m_base];
        p[0] = pack2h(acc[i][j][0] + bv, acc[i][j][1] + bv);
        p[1] = pack2h(acc[i][j][2] + bv, acc[i][j][3] + bv);
      }
    }
    __syncthreads();
    const int b = m0 >> 10;
    const int sb0 = m0 & 1023;
#pragma unroll
    for (int c = 0; c < 8; c++) {
      const int id = c * 256 + tid;
      const int n_loc = id >> 4, cm = (id & 15) * 8;
      const short8 v = *(const short8*)&smem[n_loc * 136 + cm];
      *(short8*)&vt[((size_t)(b * 1024 + n0 + n_loc) << 10) + sb0 + cm] = v;
    }
    return;
  }

  void* C = z == 0 ? C0 : C1;
#pragma unroll
  for (int j = 0; j < 4; j++) {
    const int n_loc = wn + j * 16 + l16;
    const float bv = bias[n0 + n_loc];
#pragma unroll
    for (int i = 0; i < 4; i++) {
      const int m_base = wm + i * 16 + quad * 4;
#pragma unroll
      for (int r = 0; r < 4; r++)
        ((_Float16*)smem)[(m_base + r) * 136 + n_loc] =
            (_Float16)((acc[i][j][r] + bv) * scale);
    }
  }
  __syncthreads();
#pragma unroll
  for (int c = 0; c < 8; c++) {
    const int id = c * 256 + tid;
    const int m_loc = id >> 4, cn = (id & 15) * 8;
    const short8 v = *(const short8*)&smem[m_loc * 136 + cn];
    *(short8*)&((ushort_t*)C)[(size_t)(m0 + m_loc) * N + n0 + cn] = v;
  }
}

// ---- O-projection GEMM: 128m x 64n tile, 2-phase double-buffered staging.
// LDS: As0 16K | As1 16K | Ws0 8K | Ws1 8K = 48 KB. Natural dispatch order.
__global__ __launch_bounds__(256) void gemm_o(
    const ushort_t* __restrict__ A, const ushort_t* __restrict__ W,
    const float* __restrict__ bias, void* __restrict__ C,
    int N, int K, const int* __restrict__ flags)
{
  __shared__ ushort_t smem[24576];

  const int tid  = threadIdx.x;
  const int wave = tid >> 6;
  const int lane = tid & 63;
  const int quad = lane >> 4;
  const int l16  = lane & 15;
  const int rx   = l16 & 7;
  const int wm   = (wave >> 1) * 64;
  const int wn   = (wave & 1) * 32;
  const int m0   = blockIdx.x * 128;
  const int n0   = blockIdx.y * 64;
  const bool wf32 = flags[0] != 0;

  const ushort_t* Ab = A + (size_t)m0 * K;
  const ushort_t* Wb = W + (size_t)n0 * K;

  floatx4 acc[4][2];
#pragma unroll
  for (int i = 0; i < 4; i++)
#pragma unroll
    for (int j = 0; j < 2; j++) acc[i][j] = (floatx4){0.f, 0.f, 0.f, 0.f};

  const int srow = tid >> 3;
  const int cc   = tid & 7;
  const int ldsw = wave * 512;

  auto stage_o = [&](int k0, int bsel) {
    ushort_t* Asb = smem + bsel * 8192;
    ushort_t* Wsb = smem + 16384 + bsel * 4096;
#pragma unroll
    for (int it = 0; it < 4; ++it) {
      const int row = it * 32 + srow;
      const int sw  = (cc ^ (row & 7)) * 8;
      gload_lds16(Ab + (size_t)row * K + k0 + sw, &Asb[it * 2048 + ldsw]);
      if (it < 2)
        gload_lds16(Wb + (size_t)row * K + k0 + sw, &Wsb[it * 2048 + ldsw]);
    }
  };

  stage_o(0, 0);
  __syncthreads();
  for (int k0 = 0, s = 0; k0 < K; k0 += 64, ++s) {
    const int cur = s & 1;
    if (k0 + 64 < K) stage_o(k0 + 64, cur ^ 1);   // issue-early into other buf
    const ushort_t* Asb = smem + cur * 8192;
    const ushort_t* Wsb = smem + 16384 + cur * 4096;
#pragma unroll
    for (int kk = 0; kk < 2; ++kk) {
      half8 af[4], wf[2];
#pragma unroll
      for (int i = 0; i < 4; i++)
        af[i] = *(const half8*)&Asb[(wm + i * 16 + l16) * 64 + (((kk * 4 + quad) ^ rx) * 8)];
#pragma unroll
      for (int j = 0; j < 2; j++)
        wf[j] = *(const half8*)&Wsb[(wn + j * 16 + l16) * 64 + (((kk * 4 + quad) ^ rx) * 8)];
#pragma unroll
      for (int i = 0; i < 4; i++)
#pragma unroll
        for (int j = 0; j < 2; j++)
          acc[i][j] = __builtin_amdgcn_mfma_f32_16x16x32_f16(af[i], wf[j], acc[i][j], 0, 0, 0);
    }
    __syncthreads();   // drain-late: prefetch latency was covered by MFMA
  }

  if (wf32) {
#pragma unroll
    for (int j = 0; j < 2; j++) {
      const int n = n0 + wn + j * 16 + l16;
      const float bv = bias[n];
#pragma unroll
      for (int i = 0; i < 4; i++) {
        const int mrow = m0 + wm + i * 16 + quad * 4;
#pragma unroll
        for (int r = 0; r < 4; r++)
          ((float*)C)[(size_t)(mrow + r) * N + n] = acc[i][j][r] + bv;
      }
    }
  } else {
#pragma unroll
    for (int j = 0; j < 2; j++) {
      const int n_loc = wn + j * 16 + l16;
      const float bv = bias[n0 + n_loc];
#pragma unroll
      for (int i = 0; i < 4; i++) {
        const int m_base = wm + i * 16 + quad * 4;
#pragma unroll
        for (int r = 0; r < 4; r++)
          smem[(m_base + r) * 72 + n_loc] = f2bf(acc[i][j][r] + bv);
      }
    }
    __syncthreads();
#pragma unroll
    for (int c = 0; c < 4; c++) {
      const int id = c * 256 + tid;
      const int m_loc = id >> 3, cn = (id & 7) * 8;
      const short8 v = *(const short8*)&smem[m_loc * 72 + cn];
      *(short8*)&((ushort_t*)C)[(size_t)(m0 + m_loc) * N + n0 + cn] = v;
    }
  }
}

// ---- Flash attention (f16): 512-thread blocks, t-tile 128 (8 waves x 16).
// K/V double-buffered, one barrier per tile. XCD swizzle: the 8 t-blocks
// sharing one (b,h) K/V slice land on one XCD (~2 MB/XCD, L2-resident).
__global__ __launch_bounds__(512) void attn(
    const ushort_t* __restrict__ Q, const ushort_t* __restrict__ K,
    const ushort_t* __restrict__ Vt,
    const float* __restrict__ mvG, const float* __restrict__ mvL,
    ushort_t* __restrict__ O)
{
  __shared__ ushort_t Qs[128 * 64];
  __shared__ ushort_t Ks[2][64 * 64];
  __shared__ ushort_t Vs[2][64 * 64];
  __shared__ float mvb[S_];
  __shared__ _Float16 Ps[8][16 * 72];

  // XCD swizzle: 512 blocks, cpx=64; decode (t,h,b) from swizzled id.
  const int orig = (blockIdx.z * 16 + blockIdx.y) * 8 + blockIdx.x;
  const int swz  = (orig & 7) * 64 + (orig >> 3);
  const int t0 = (swz & 7) * 128;
  const int h  = (swz >> 3) & 15;
  const int b  = swz >> 7;

  const int tid = threadIdx.x, wave = tid >> 6, lane = tid & 63;
  const int quad = lane >> 4, l16 = lane & 15;
  const int rx = l16 & 7;

  const float* msel = (h < (H_ / 2)) ? mvG : mvL;
  ((float2v*)mvb)[tid] = ((const float2v*)(msel + b * S_))[tid];

  const int srow = tid >> 3, cc = tid & 7;
  const int sc8 = (cc ^ (srow & 7)) * 8;

  const ushort_t* Kb = K + (size_t)b * S_ * E_ + h * DH_;
  const ushort_t* Vb = Vt + (size_t)((b * H_ + h) * DH_) * S_;

  auto stageKV = [&](int st, int bsel) {
    const int s0 = st * 64;
    gload_lds16(Kb + (size_t)(s0 + srow) * E_ + sc8, &Ks[bsel][wave * 512]);
    gload_lds16(Vb + (size_t)srow * S_ + s0 + sc8, &Vs[bsel][wave * 512]);
  };

  const ushort_t* Qb = Q + (size_t)(b * T_ + t0) * E_ + h * DH_;
#pragma unroll
  for (int it = 0; it < 2; ++it) {
    const int row = it * 64 + srow;
    gload_lds16(Qb + (size_t)row * E_ + ((cc ^ (row & 7)) * 8),
                &Qs[it * 4096 + wave * 512]);
  }
  stageKV(0, 0);
  __syncthreads();

  const half8 qf0 = *(const half8*)&Qs[(wave * 16 + l16) * 64 + ((quad ^ rx) * 8)];
  const half8 qf1 = *(const half8*)&Qs[(wave * 16 + l16) * 64 + (((quad + 4) ^ rx) * 8)];

  float lsum[4];
  floatx4 oa[4];
#pragma unroll
  for (int r = 0; r < 4; r++) lsum[r] = 0.0f;
#pragma unroll
  for (int i = 0; i < 4; i++) oa[i] = (floatx4){0.f, 0.f, 0.f, 0.f};

  for (int st = 0; st < 16; ++st) {
    const int cur = st & 1;
    if (st + 1 < 16) stageKV(st + 1, cur ^ 1);   // issue-early into other buf
    const int s0 = st * 64;

    floatx4 sc[4];
#pragma unroll
    for (int j = 0; j < 4; j++) {
      const half8 kf0 = *(const half8*)&Ks[cur][(j * 16 + l16) * 64 + ((quad ^ rx) * 8)];
      const half8 kf1 = *(const half8*)&Ks[cur][(j * 16 + l16) * 64 + (((quad + 4) ^ rx) * 8)];
      floatx4 zz = (floatx4){0.f, 0.f, 0.f, 0.f};
      zz = __builtin_amdgcn_mfma_f32_16x16x32_f16(qf0, kf0, zz, 0, 0, 0);
      zz = __builtin_amdgcn_mfma_f32_16x16x32_f16(qf1, kf1, zz, 0, 0, 0);
      sc[j] = zz;
    }

#pragma unroll
    for (int j = 0; j < 4; j++) {
      const float mv = mvb[s0 + j * 16 + l16];
#pragma unroll
      for (int r = 0; r < 4; r++) {
        const float p = exp2f(fmaf(sc[j][r], L2E_, mv));
        lsum[r] += p;
        Ps[wave][(quad * 4 + r) * 72 + j * 16 + l16] = (_Float16)p;
      }
    }

    const half8 pa0 = *(const half8*)&Ps[wave][l16 * 72 + quad * 8];
    const half8 pa1 = *(const half8*)&Ps[wave][l16 * 72 + 32 + quad * 8];
#pragma unroll
    for (int i = 0; i < 4; i++) {
      const half8 vb0 = *(const half8*)&Vs[cur][(i * 16 + l16) * 64 + ((quad ^ rx) * 8)];
      const half8 vb1 = *(const half8*)&Vs[cur][(i * 16 + l16) * 64 + (((quad + 4) ^ rx) * 8)];
      oa[i] = __builtin_amdgcn_mfma_f32_16x16x32_f16(pa0, vb0, oa[i], 0, 0, 0);
      oa[i] = __builtin_amdgcn_mfma_f32_16x16x32_f16(pa1, vb1, oa[i], 0, 0, 0);
    }

    __syncthreads();   // drain prefetch (covered by compute) + buf handoff
  }

#pragma unroll
  for (int r = 0; r < 4; r++) {
#pragma unroll
    for (int off = 1; off < 16; off <<= 1) lsum[r] += __shfl_xor(lsum[r], off, 64);
    const float inv = (lsum[r] > 0.0f) ? (1.0f / lsum[r]) : 0.0f;
    const int trow = t0 + wave * 16 + quad * 4 + r;
#pragma unroll
    for (int i = 0; i < 4; i++)
      ((_Float16*)O)[(size_t)(b * T_ + trow) * E_ + h * DH_ + i * 16 + l16] =
          (_Float16)(oa[i][r] * inv);
  }
}

extern "C" void kernel_launch(void* const* d_in, const int* in_sizes, int n_in,
                              void* d_out, int out_size, void* d_ws, size_t ws_size,
                              hipStream_t stream)
{
  const void* query = d_in[0];
  const void* key   = d_in[1];
  const void* value = d_in[2];
  const int* kpm    = (const int*)d_in[3];
  const int* lm     = (const int*)d_in[4];
  const void* Wq    = d_in[5];
  const void* bq    = d_in[6];
  const void* Wk    = d_in[7];
  const void* bk    = d_in[8];
  const void* Wv    = d_in[9];
  const void* bv    = d_in[10];
  const void* Wo    = d_in[11];
  const void* bo    = d_in[12];

  const size_t NE = (size_t)B_ * T_ * E_;   // 4M elements
  const size_t WE = (size_t)E_ * E_;        // 1M elements

  char* ws = (char*)d_ws;
  int*      flags  = (int*)ws;                               // 1 KB
  float*    mvG    = (float*)(ws + 1024);                    // 16 KB
  float*    mvL    = mvG + B_ * S_;                          // 16 KB
  float*    B4     = (float*)(ws + 64 * 1024);               // 16 KB
  ushort_t* W4     = (ushort_t*)(ws + 96 * 1024);            // 8 MB (f16)
  ushort_t* q_in   = (ushort_t*)(ws + 96 * 1024 + (8u << 20));  // f16 qkv
  ushort_t* k_in   = q_in + NE;
  ushort_t* v_in   = k_in + NE;
  ushort_t* q_buf  = v_in + NE;
  ushort_t* k_buf  = q_buf + NE;
  ushort_t* vt_buf = k_buf + NE;
  ushort_t* o_buf  = q_in;   // q_in dead after QKV gemm

  const float SCALING = 0.125f;  // DH^-0.5

  prep_convert<<<1024, 256, 0, stream>>>(
      query, key, value, Wq, Wk, Wv, Wo, bq, bk, bv, bo, kpm, lm,
      flags, B4, mvG, mvL, (uint4v*)q_in, (uint4v*)W4);
  gemm_bt<<<dim3(32, 8, 3), 256, 0, stream>>>(
      q_in, k_in, v_in,
      W4, W4 + WE, W4 + 2 * WE, B4, B4 + 1024, B4 + 2048,
      q_buf, k_buf, vt_buf, E_, E_, SCALING);
  attn<<<dim3(8, 16, 4), 512, 0, stream>>>(q_buf, k_buf, vt_buf, mvG, mvL, o_buf);
  gemm_o<<<dim3(32, 16), 256, 0, stream>>>(
      o_buf, W4 + 3 * WE, B4 + 3072, d_out, E_, E_, flags);
}